// Round 3
// baseline (879.197 us; speedup 1.0000x reference)
//
#include <hip/hip_runtime.h>
#include <math.h>

// ============ counting-sort of edges by col (CSR build), then gather ============
// Device-scope fp32 atomics execute at the memory-side coherence point on MI355X
// (k_scatter: 51.2M atomics -> 200MB write-through, 314G atomics/s ceiling, 163us).
// A col-sorted CSR turns both aggregation layers into plain gather+store kernels.
#define HB   16384   // bins per partition = 64KB LDS
#define HBL  14
#define BPP  32      // blocks per partition (chunk = E/32 = 100K edges, fits u32)

typedef unsigned int uint;

// ---- pass 1: per (partition, block) count histogram of col ----
__global__ __launch_bounds__(256) void k_cnt_hist(const int* __restrict__ col,
                                                  uint* __restrict__ cnt, int E) {
    __shared__ uint bins[HB];
    int p = blockIdx.y, base = p << HBL;
    for (int i = threadIdx.x; i < HB; i += 256) bins[i] = 0u;
    __syncthreads();
    int chunk = (E + BPP - 1) / BPP;
    int e0 = blockIdx.x * chunk, e1 = min(E, e0 + chunk);
    for (int e = e0 + threadIdx.x; e < e1; e += 256) {
        int c = col[e] - base;
        if ((unsigned)c < (unsigned)HB) atomicAdd(&bins[c], 1u);
    }
    __syncthreads();
    uint* out = cnt + ((size_t)(p * BPP + blockIdx.x) << HBL);
    for (int i = threadIdx.x; i < HB; i += 256) out[i] = bins[i];
}

// ---- pass 2: per (p,bin) exclusive prefix over blocks (in-place) + bin totals ----
__global__ void k_binsum(uint* __restrict__ cnt, uint* __restrict__ tot, int M) {
    int idx = blockIdx.x * blockDim.x + threadIdx.x;
    if (idx >= M) return;
    int p = idx >> HBL, bin = idx & (HB - 1);
    uint* q = cnt + ((size_t)(p * BPP) << HBL) + bin;
    uint s = 0;
#pragma unroll 8
    for (int b = 0; b < BPP; b++) {
        uint v = q[(size_t)b << HBL];
        q[(size_t)b << HBL] = s;
        s += v;
    }
    tot[idx] = s;   // tot == bin_base array, scanned in place next
}

// ---- pass 3: exclusive scan of bin totals (2-level, in place) ----
__global__ __launch_bounds__(256) void k_scan1(uint* __restrict__ a,
                                               uint* __restrict__ bs, int M) {
    __shared__ uint s[256];
    int idx = blockIdx.x * 256 + threadIdx.x;
    uint v = (idx < M) ? a[idx] : 0u;
    s[threadIdx.x] = v;
    __syncthreads();
    for (int off = 1; off < 256; off <<= 1) {
        uint x = (threadIdx.x >= off) ? s[threadIdx.x - off] : 0u;
        __syncthreads();
        s[threadIdx.x] += x;
        __syncthreads();
    }
    if (idx < M) a[idx] = s[threadIdx.x] - v;          // exclusive within block
    if (threadIdx.x == 255) bs[blockIdx.x] = s[255];   // block total
}

__global__ __launch_bounds__(256) void k_scan2(uint* __restrict__ bs, int n) {
    __shared__ uint s[256];
    __shared__ uint carry;
    if (threadIdx.x == 0) carry = 0;
    __syncthreads();
    for (int base = 0; base < n; base += 256) {
        int i = base + threadIdx.x;
        uint v = (i < n) ? bs[i] : 0u;
        s[threadIdx.x] = v;
        __syncthreads();
        for (int off = 1; off < 256; off <<= 1) {
            uint x = (threadIdx.x >= off) ? s[threadIdx.x - off] : 0u;
            __syncthreads();
            s[threadIdx.x] += x;
            __syncthreads();
        }
        uint c = carry;
        if (i < n) bs[i] = c + s[threadIdx.x] - v;     // exclusive global
        __syncthreads();
        if (threadIdx.x == 255) carry = c + s[255];
        __syncthreads();
    }
}

__global__ void k_scan3(uint* __restrict__ a, const uint* __restrict__ bs, int M) {
    int idx = blockIdx.x * blockDim.x + threadIdx.x;
    if (idx < M) a[idx] += bs[blockIdx.x];
}

// ---- pass 4: scatter edges into sorted position (LDS cursors, no global atomics) ----
__global__ __launch_bounds__(256) void k_sortscatter(const int* __restrict__ row,
        const int* __restrict__ col, const float* __restrict__ w,
        const uint* __restrict__ cnt, const uint* __restrict__ bb,
        int2* __restrict__ sorted, int E) {
    __shared__ uint cur[HB];
    int p = blockIdx.y, base = p << HBL;
    const uint* myc  = cnt + ((size_t)(p * BPP + blockIdx.x) << HBL);
    const uint* mybb = bb + ((size_t)p << HBL);
    for (int i = threadIdx.x; i < HB; i += 256) cur[i] = myc[i] + mybb[i];
    __syncthreads();
    int chunk = (E + BPP - 1) / BPP;
    int e0 = blockIdx.x * chunk, e1 = min(E, e0 + chunk);
    for (int e = e0 + threadIdx.x; e < e1; e += 256) {
        int c = col[e] - base;
        if ((unsigned)c < (unsigned)HB) {
            uint slot = atomicAdd(&cur[c], 1u);
            sorted[slot] = make_int2(row[e], __float_as_int(w[e]));
        }
    }
}

// ---- dv[n] = rsqrt(1 + segment-sum of sorted w) ----
__global__ void k_deg_dv(const int2* __restrict__ sorted, const uint* __restrict__ bb,
                         float* __restrict__ dv, int N, int E, int M) {
    int n = blockIdx.x * blockDim.x + threadIdx.x;
    if (n >= N) return;
    uint s0 = bb[n];
    uint s1 = (n + 1 < M) ? bb[n + 1] : (uint)E;
    float s = 1.0f;                       // self-loop weight
    for (uint k = s0; k < s1; k++) s += __int_as_float(sorted[k].y);
    dv[n] = rsqrtf(s);
}

// ---------------- x @ W1  (N x 256 @ 256 x 16) ----------------
__global__ __launch_bounds__(256) void k_xw1(const float* __restrict__ x,
                                             const float* __restrict__ W1,
                                             float* __restrict__ h, int N) {
    __shared__ float xs[16][257];
    __shared__ float wsh[256 * 16];
    int t = threadIdx.x;
    int base = blockIdx.x * 16;

    const float4* w4 = (const float4*)W1;
    float4* wsh4 = (float4*)wsh;
#pragma unroll
    for (int i = 0; i < 4; i++) wsh4[t + i * 256] = w4[t + i * 256];

    const float4* x4 = (const float4*)x;
    long xbase4 = (long)base * 64;
#pragma unroll
    for (int i = 0; i < 4; i++) {
        int p4 = t + i * 256;
        int r = p4 >> 6;
        int k = (p4 & 63) * 4;
        if (base + r < N) {
            float4 v = x4[xbase4 + p4];
            xs[r][k] = v.x; xs[r][k + 1] = v.y; xs[r][k + 2] = v.z; xs[r][k + 3] = v.w;
        }
    }
    __syncthreads();

    int r = t >> 4, j = t & 15;
    if (base + r < N) {
        float acc = 0.f;
#pragma unroll
        for (int k = 0; k < 256; k++) acc += xs[r][k] * wsh[k * 16 + j];
        h[(long)(base + r) * 16 + j] = acc;
    }
}

// ---- layer1: h1 = relu(self + gather + b1); wave per node, 4 edges x 16 feats ----
__global__ __launch_bounds__(256) void k_gather_l1(const int2* __restrict__ sorted,
        const uint* __restrict__ bb, const float* __restrict__ dv,
        const float* __restrict__ h, const float* __restrict__ b1,
        float* __restrict__ ho, int N, int E, int M) {
    int wave = threadIdx.x >> 6;
    int node = blockIdx.x * 4 + wave;
    if (node >= N) return;
    int lane = threadIdx.x & 63;
    int es = lane >> 4, j = lane & 15;
    uint s0 = bb[node];
    uint s1 = (node + 1 < M) ? bb[node + 1] : (uint)E;
    float dvn = dv[node];
    float acc = 0.f;
    for (uint k = s0 + es; k < s1; k += 4) {
        int2 pr = sorted[k];
        float nr = dv[pr.x] * __int_as_float(pr.y) * dvn;
        acc += nr * h[(size_t)pr.x * 16 + j];
    }
    acc += __shfl_xor(acc, 16);
    acc += __shfl_xor(acc, 32);
    acc += dvn * dvn * h[(size_t)node * 16 + j] + b1[j];
    acc = fmaxf(acc, 0.f);
    if (es == 0) ho[(size_t)node * 16 + j] = acc;
}

// ---- layer2 fused with @W2 + b2 + log_softmax epilogue ----
__global__ __launch_bounds__(256) void k_gather_l2out(const int2* __restrict__ sorted,
        const uint* __restrict__ bb, const float* __restrict__ dv,
        const float* __restrict__ h, const float* __restrict__ W2,
        const float* __restrict__ b2, float* __restrict__ out, int N, int E, int M) {
    int wave = threadIdx.x >> 6;
    int node = blockIdx.x * 4 + wave;
    if (node >= N) return;
    int lane = threadIdx.x & 63;
    int es = lane >> 4, j = lane & 15;
    uint s0 = bb[node];
    uint s1 = (node + 1 < M) ? bb[node + 1] : (uint)E;
    float dvn = dv[node];
    float acc = 0.f;
    for (uint k = s0 + es; k < s1; k += 4) {
        int2 pr = sorted[k];
        float nr = dv[pr.x] * __int_as_float(pr.y) * dvn;
        acc += nr * h[(size_t)pr.x * 16 + j];
    }
    acc += __shfl_xor(acc, 16);
    acc += __shfl_xor(acc, 32);
    acc += dvn * dvn * h[(size_t)node * 16 + j];   // agg2_j (replicated over es)

    float aj[16];
#pragma unroll
    for (int q = 0; q < 16; q++) aj[q] = __shfl(acc, q);  // lane q<16 holds total for feat q
    float logit = -INFINITY;
    if (lane < 40) {
        logit = b2[lane];
#pragma unroll
        for (int q = 0; q < 16; q++) logit += aj[q] * W2[q * 40 + lane];
    }
    float m = logit;
#pragma unroll
    for (int off = 32; off; off >>= 1) m = fmaxf(m, __shfl_xor(m, off));
    float ex = (lane < 40) ? expf(logit - m) : 0.f;
    float ssum = ex;
#pragma unroll
    for (int off = 32; off; off >>= 1) ssum += __shfl_xor(ssum, off);
    if (lane < 40) out[(size_t)node * 40 + lane] = logit - m - logf(ssum);
}

extern "C" void kernel_launch(void* const* d_in, const int* in_sizes, int n_in,
                              void* d_out, int out_size, void* d_ws, size_t ws_size,
                              hipStream_t stream) {
    const float* x  = (const float*)d_in[0];
    const int*   ei = (const int*)d_in[1];
    const float* ew = (const float*)d_in[2];
    const float* W1 = (const float*)d_in[3];
    const float* b1 = (const float*)d_in[4];
    const float* W2 = (const float*)d_in[5];
    const float* b2 = (const float*)d_in[6];
    float* out = (float*)d_out;

    int N = in_sizes[0] / 256;
    int E = in_sizes[2];
    const int* row = ei;
    const int* col = ei + E;

    int P = (N + HB - 1) >> HBL;           // 7 partitions for N=100000
    int M = P << HBL;                      // 114688 bins total

    // workspace layout (u32 units), peak ~41.2MB:
    //   sorted   : 2E            (25.6MB, live whole launch)
    //   cnt      : P*BPP*HB      (14.7MB, dead after sortscatter -> reused for h, h1)
    //   bin_base : M             (0.46MB, = CSR offsets, live whole launch)
    //   blk_sums : 1024
    //   dv       : N floats
    uint* ws32 = (uint*)d_ws;
    int2* sorted = (int2*)ws32;
    uint* cnt = ws32 + 2 * (size_t)E;
    uint* bb  = cnt + ((size_t)(P * BPP) << HBL);
    uint* bs  = bb + M;
    float* dv = (float*)(bs + 1024);
    float* h   = (float*)cnt;              // N*16 floats (6.4MB)  -- reuse cnt
    float* h1r = h + (size_t)N * 16;       // N*16 floats (6.4MB)  -- still inside cnt

    int nblk = (M + 255) / 256;

    k_cnt_hist    <<<dim3(BPP, P), 256, 0, stream>>>(col, cnt, E);
    k_binsum      <<<nblk, 256, 0, stream>>>(cnt, bb, M);
    k_scan1       <<<nblk, 256, 0, stream>>>(bb, bs, M);
    k_scan2       <<<1, 256, 0, stream>>>(bs, nblk);
    k_scan3       <<<nblk, 256, 0, stream>>>(bb, bs, M);
    k_sortscatter <<<dim3(BPP, P), 256, 0, stream>>>(row, col, ew, cnt, bb, sorted, E);
    k_deg_dv      <<<(N + 255) / 256, 256, 0, stream>>>(sorted, bb, dv, N, E, M);
    k_xw1         <<<(N + 15) / 16, 256, 0, stream>>>(x, W1, h, N);
    k_gather_l1   <<<(N + 3) / 4, 256, 0, stream>>>(sorted, bb, dv, h, b1, h1r, N, E, M);
    k_gather_l2out<<<(N + 3) / 4, 256, 0, stream>>>(sorted, bb, dv, h1r, W2, b2, out, N, E, M);
}

// Round 4
// 599.997 us; speedup vs baseline: 1.4653x; 1.4653x over previous
//
#include <hip/hip_runtime.h>
#include <math.h>

// ============ counting-sort of edges by col (CSR build), then gather ============
// Atomic-scatter baseline: 51.2M device atomics -> 200MB write-through, 163us x2.
// CSR + gather removes all global atomics. Round-3 lesson: BPP=32,HB=16K gave only
// 224 blocks (<1 block/CU, 9.9% occupancy) -> sortscatter latency-bound at 289us.
// Fix: HB=8192 (32KB LDS, 5 blocks/CU) + BPP=64 (832 blocks) + int4 edge loads (ILP).
#define HB   8192    // bins per partition = 32KB LDS
#define HBL  13
#define BPP  64      // blocks per partition

typedef unsigned int uint;

// ---- pass 1: per (partition, block) count histogram of col ----
__global__ __launch_bounds__(256) void k_cnt_hist(const int* __restrict__ col,
                                                  uint* __restrict__ cnt, int E) {
    __shared__ uint bins[HB];
    int p = blockIdx.y, base = p << HBL;
    for (int i = threadIdx.x; i < HB; i += 256) bins[i] = 0u;
    __syncthreads();
    int chunk = (((E + BPP - 1) / BPP) + 3) & ~3;
    int e0 = blockIdx.x * chunk, e1 = min(E, e0 + chunk);
    for (int e = e0 + threadIdx.x * 4; e < e1; e += 1024) {
        int4 c4;
        if (e + 3 < e1) c4 = *(const int4*)(col + e);
        else {
            c4.x = col[e];
            c4.y = (e + 1 < e1) ? col[e + 1] : -1;
            c4.z = (e + 2 < e1) ? col[e + 2] : -1;
            c4.w = (e + 3 < e1) ? col[e + 3] : -1;
        }
        int a = c4.x - base, b = c4.y - base, c = c4.z - base, d = c4.w - base;
        if ((unsigned)a < (unsigned)HB) atomicAdd(&bins[a], 1u);
        if ((unsigned)b < (unsigned)HB) atomicAdd(&bins[b], 1u);
        if ((unsigned)c < (unsigned)HB) atomicAdd(&bins[c], 1u);
        if ((unsigned)d < (unsigned)HB) atomicAdd(&bins[d], 1u);
    }
    __syncthreads();
    uint* out = cnt + ((size_t)(p * BPP + blockIdx.x) << HBL);
    for (int i = threadIdx.x; i < HB; i += 256) out[i] = bins[i];
}

// ---- pass 2: per (p,bin) exclusive prefix over blocks (in-place) + bin totals ----
__global__ void k_binsum(uint* __restrict__ cnt, uint* __restrict__ tot, int M) {
    int idx = blockIdx.x * blockDim.x + threadIdx.x;
    if (idx >= M) return;
    int p = idx >> HBL, bin = idx & (HB - 1);
    uint* q = cnt + ((size_t)(p * BPP) << HBL) + bin;
    uint s = 0;
#pragma unroll 8
    for (int b = 0; b < BPP; b++) {
        uint v = q[(size_t)b << HBL];
        q[(size_t)b << HBL] = s;
        s += v;
    }
    tot[idx] = s;   // tot == bin_base array, scanned in place next
}

// ---- pass 3: exclusive scan of bin totals (2-level, in place) ----
__global__ __launch_bounds__(256) void k_scan1(uint* __restrict__ a,
                                               uint* __restrict__ bs, int M) {
    __shared__ uint s[256];
    int idx = blockIdx.x * 256 + threadIdx.x;
    uint v = (idx < M) ? a[idx] : 0u;
    s[threadIdx.x] = v;
    __syncthreads();
    for (int off = 1; off < 256; off <<= 1) {
        uint x = (threadIdx.x >= off) ? s[threadIdx.x - off] : 0u;
        __syncthreads();
        s[threadIdx.x] += x;
        __syncthreads();
    }
    if (idx < M) a[idx] = s[threadIdx.x] - v;          // exclusive within block
    if (threadIdx.x == 255) bs[blockIdx.x] = s[255];   // block total
}

__global__ __launch_bounds__(256) void k_scan2(uint* __restrict__ bs, int n) {
    __shared__ uint s[256];
    __shared__ uint carry;
    if (threadIdx.x == 0) carry = 0;
    __syncthreads();
    for (int base = 0; base < n; base += 256) {
        int i = base + threadIdx.x;
        uint v = (i < n) ? bs[i] : 0u;
        s[threadIdx.x] = v;
        __syncthreads();
        for (int off = 1; off < 256; off <<= 1) {
            uint x = (threadIdx.x >= off) ? s[threadIdx.x - off] : 0u;
            __syncthreads();
            s[threadIdx.x] += x;
            __syncthreads();
        }
        uint c = carry;
        if (i < n) bs[i] = c + s[threadIdx.x] - v;     // exclusive global
        __syncthreads();
        if (threadIdx.x == 255) carry = c + s[255];
        __syncthreads();
    }
}

__global__ void k_scan3(uint* __restrict__ a, const uint* __restrict__ bs, int M) {
    int idx = blockIdx.x * blockDim.x + threadIdx.x;
    if (idx < M) a[idx] += bs[blockIdx.x];
}

// ---- pass 4: scatter edges into sorted position (LDS cursors, no global atomics) ----
__global__ __launch_bounds__(256) void k_sortscatter(const int* __restrict__ row,
        const int* __restrict__ col, const float* __restrict__ w,
        const uint* __restrict__ cnt, const uint* __restrict__ bb,
        int2* __restrict__ sorted, int E) {
    __shared__ uint cur[HB];
    int p = blockIdx.y, base = p << HBL;
    const uint* myc  = cnt + ((size_t)(p * BPP + blockIdx.x) << HBL);
    const uint* mybb = bb + ((size_t)p << HBL);
    for (int i = threadIdx.x; i < HB; i += 256) cur[i] = myc[i] + mybb[i];
    __syncthreads();
    int chunk = (((E + BPP - 1) / BPP) + 3) & ~3;
    int e0 = blockIdx.x * chunk, e1 = min(E, e0 + chunk);
    for (int e = e0 + threadIdx.x * 4; e < e1; e += 1024) {
        int4 c4;
        if (e + 3 < e1) c4 = *(const int4*)(col + e);
        else {
            c4.x = col[e];
            c4.y = (e + 1 < e1) ? col[e + 1] : -1;
            c4.z = (e + 2 < e1) ? col[e + 2] : -1;
            c4.w = (e + 3 < e1) ? col[e + 3] : -1;
        }
        int cc[4] = {c4.x - base, c4.y - base, c4.z - base, c4.w - base};
#pragma unroll
        for (int k = 0; k < 4; k++) {
            if ((unsigned)cc[k] < (unsigned)HB) {
                uint slot = atomicAdd(&cur[cc[k]], 1u);
                sorted[slot] = make_int2(row[e + k], __float_as_int(w[e + k]));
            }
        }
    }
}

// ---- dv[n] = rsqrt(1 + segment-sum of sorted w) ----
__global__ void k_deg_dv(const int2* __restrict__ sorted, const uint* __restrict__ bb,
                         float* __restrict__ dv, int N, int E, int M) {
    int n = blockIdx.x * blockDim.x + threadIdx.x;
    if (n >= N) return;
    uint s0 = bb[n];
    uint s1 = (n + 1 < M) ? bb[n + 1] : (uint)E;
    float s = 1.0f;                       // self-loop weight
    for (uint k = s0; k < s1; k++) s += __int_as_float(sorted[k].y);
    dv[n] = rsqrtf(s);
}

// ---------------- x @ W1  (N x 256 @ 256 x 16) ----------------
__global__ __launch_bounds__(256) void k_xw1(const float* __restrict__ x,
                                             const float* __restrict__ W1,
                                             float* __restrict__ h, int N) {
    __shared__ float xs[16][257];
    __shared__ float wsh[256 * 16];
    int t = threadIdx.x;
    int base = blockIdx.x * 16;

    const float4* w4 = (const float4*)W1;
    float4* wsh4 = (float4*)wsh;
#pragma unroll
    for (int i = 0; i < 4; i++) wsh4[t + i * 256] = w4[t + i * 256];

    const float4* x4 = (const float4*)x;
    long xbase4 = (long)base * 64;
#pragma unroll
    for (int i = 0; i < 4; i++) {
        int p4 = t + i * 256;
        int r = p4 >> 6;
        int k = (p4 & 63) * 4;
        if (base + r < N) {
            float4 v = x4[xbase4 + p4];
            xs[r][k] = v.x; xs[r][k + 1] = v.y; xs[r][k + 2] = v.z; xs[r][k + 3] = v.w;
        }
    }
    __syncthreads();

    int r = t >> 4, j = t & 15;
    if (base + r < N) {
        float acc = 0.f;
#pragma unroll
        for (int k = 0; k < 256; k++) acc += xs[r][k] * wsh[k * 16 + j];
        h[(long)(base + r) * 16 + j] = acc;
    }
}

// ---- layer1: h1 = relu(self + gather + b1); wave per node, 4 edges x 16 feats ----
__global__ __launch_bounds__(256) void k_gather_l1(const int2* __restrict__ sorted,
        const uint* __restrict__ bb, const float* __restrict__ dv,
        const float* __restrict__ h, const float* __restrict__ b1,
        float* __restrict__ ho, int N, int E, int M) {
    int wave = threadIdx.x >> 6;
    int node = blockIdx.x * 4 + wave;
    if (node >= N) return;
    int lane = threadIdx.x & 63;
    int es = lane >> 4, j = lane & 15;
    uint s0 = bb[node];
    uint s1 = (node + 1 < M) ? bb[node + 1] : (uint)E;
    float dvn = dv[node];
    float acc = 0.f;
    for (uint k = s0 + es; k < s1; k += 4) {
        int2 pr = sorted[k];
        float nr = dv[pr.x] * __int_as_float(pr.y) * dvn;
        acc += nr * h[(size_t)pr.x * 16 + j];
    }
    acc += __shfl_xor(acc, 16);
    acc += __shfl_xor(acc, 32);
    acc += dvn * dvn * h[(size_t)node * 16 + j] + b1[j];
    acc = fmaxf(acc, 0.f);
    if (es == 0) ho[(size_t)node * 16 + j] = acc;
}

// ---- layer2 fused with @W2 + b2 + log_softmax epilogue ----
__global__ __launch_bounds__(256) void k_gather_l2out(const int2* __restrict__ sorted,
        const uint* __restrict__ bb, const float* __restrict__ dv,
        const float* __restrict__ h, const float* __restrict__ W2,
        const float* __restrict__ b2, float* __restrict__ out, int N, int E, int M) {
    int wave = threadIdx.x >> 6;
    int node = blockIdx.x * 4 + wave;
    if (node >= N) return;
    int lane = threadIdx.x & 63;
    int es = lane >> 4, j = lane & 15;
    uint s0 = bb[node];
    uint s1 = (node + 1 < M) ? bb[node + 1] : (uint)E;
    float dvn = dv[node];
    float acc = 0.f;
    for (uint k = s0 + es; k < s1; k += 4) {
        int2 pr = sorted[k];
        float nr = dv[pr.x] * __int_as_float(pr.y) * dvn;
        acc += nr * h[(size_t)pr.x * 16 + j];
    }
    acc += __shfl_xor(acc, 16);
    acc += __shfl_xor(acc, 32);
    acc += dvn * dvn * h[(size_t)node * 16 + j];   // agg2_j (replicated over es)

    float aj[16];
#pragma unroll
    for (int q = 0; q < 16; q++) aj[q] = __shfl(acc, q);  // lane q<16 holds total for feat q
    float logit = -INFINITY;
    if (lane < 40) {
        logit = b2[lane];
#pragma unroll
        for (int q = 0; q < 16; q++) logit += aj[q] * W2[q * 40 + lane];
    }
    float m = logit;
#pragma unroll
    for (int off = 32; off; off >>= 1) m = fmaxf(m, __shfl_xor(m, off));
    float ex = (lane < 40) ? expf(logit - m) : 0.f;
    float ssum = ex;
#pragma unroll
    for (int off = 32; off; off >>= 1) ssum += __shfl_xor(ssum, off);
    if (lane < 40) out[(size_t)node * 40 + lane] = logit - m - logf(ssum);
}

extern "C" void kernel_launch(void* const* d_in, const int* in_sizes, int n_in,
                              void* d_out, int out_size, void* d_ws, size_t ws_size,
                              hipStream_t stream) {
    const float* x  = (const float*)d_in[0];
    const int*   ei = (const int*)d_in[1];
    const float* ew = (const float*)d_in[2];
    const float* W1 = (const float*)d_in[3];
    const float* b1 = (const float*)d_in[4];
    const float* W2 = (const float*)d_in[5];
    const float* b2 = (const float*)d_in[6];
    float* out = (float*)d_out;

    int N = in_sizes[0] / 256;
    int E = in_sizes[2];
    const int* row = ei;
    const int* col = ei + E;

    int P = (N + HB - 1) >> HBL;           // 13 partitions for N=100000
    int M = P << HBL;                      // 106496 bins total

    // workspace layout (u32 units), peak ~54MB:
    //   sorted   : 2E            (25.6MB, live whole launch)
    //   cnt      : P*BPP*HB      (27.3MB, dead after sortscatter -> reused for h, h1)
    //   bin_base : M             (0.43MB, = CSR offsets, live whole launch)
    //   blk_sums : 1024
    //   dv       : N floats
    uint* ws32 = (uint*)d_ws;
    int2* sorted = (int2*)ws32;
    uint* cnt = ws32 + 2 * (size_t)E;
    uint* bb  = cnt + ((size_t)(P * BPP) << HBL);
    uint* bs  = bb + M;
    float* dv = (float*)(bs + 1024);
    float* h   = (float*)cnt;              // N*16 floats (6.4MB)  -- reuse cnt
    float* h1r = h + (size_t)N * 16;       // N*16 floats (6.4MB)  -- still inside cnt

    int nblk = (M + 255) / 256;            // 416 <= 1024 bs slots

    k_cnt_hist    <<<dim3(BPP, P), 256, 0, stream>>>(col, cnt, E);
    k_binsum      <<<nblk, 256, 0, stream>>>(cnt, bb, M);
    k_scan1       <<<nblk, 256, 0, stream>>>(bb, bs, M);
    k_scan2       <<<1, 256, 0, stream>>>(bs, nblk);
    k_scan3       <<<nblk, 256, 0, stream>>>(bb, bs, M);
    k_sortscatter <<<dim3(BPP, P), 256, 0, stream>>>(row, col, ew, cnt, bb, sorted, E);
    k_deg_dv      <<<(N + 255) / 256, 256, 0, stream>>>(sorted, bb, dv, N, E, M);
    k_xw1         <<<(N + 15) / 16, 256, 0, stream>>>(x, W1, h, N);
    k_gather_l1   <<<(N + 3) / 4, 256, 0, stream>>>(sorted, bb, dv, h, b1, h1r, N, E, M);
    k_gather_l2out<<<(N + 3) / 4, 256, 0, stream>>>(sorted, bb, dv, h1r, W2, b2, out, N, E, M);
}